// Round 3
// baseline (862.395 us; speedup 1.0000x reference)
//
#include <hip/hip_runtime.h>
#include <hip/hip_bf16.h>
#include <stdint.h>
#include <math.h>

// SparseMoeBlock: 8 experts, top-2, H=2048, I=1408, T=8192, fp32 in/out.
// R3: 256x256 8-wave fine-phase GEMMs (4 quadrant phases/K-tile, raw
// s_barriers, single drain per K-tile at phase 4), gate/up interleaved in
// B tile for lane-local silu epilogue, j-outer/m-inner + XCD chunking.

#define E_ 8
#define H_ 2048
#define I_ 1408
#define T_ 8192
#define NSLOT (T_ * 2)

typedef __bf16 bf16;
typedef bf16 bf16x4 __attribute__((ext_vector_type(4)));
typedef bf16 bf16x8 __attribute__((ext_vector_type(8)));
typedef float f32x4 __attribute__((ext_vector_type(4)));

__device__ inline void gl2lds16(const void* g, void* l) {
  __builtin_amdgcn_global_load_lds(
      (const __attribute__((address_space(1))) unsigned int*)g,
      (__attribute__((address_space(3))) unsigned int*)l, 16, 0, 0);
}
__device__ __forceinline__ void bar_() { asm volatile("s_barrier" ::: "memory"); }

// ---------------- fp32 -> bf16 conversion (weights) ----------------
__global__ __launch_bounds__(256) void cvt_k(const float* __restrict__ in,
                                             bf16* __restrict__ out, int n8) {
  int stride = gridDim.x * blockDim.x;
  for (int i = blockIdx.x * blockDim.x + threadIdx.x; i < n8; i += stride) {
    const float4* p = (const float4*)in + (size_t)i * 2;
    float4 a = p[0], b = p[1];
    bf16x8 o;
    o[0] = (bf16)a.x; o[1] = (bf16)a.y; o[2] = (bf16)a.z; o[3] = (bf16)a.w;
    o[4] = (bf16)b.x; o[5] = (bf16)b.y; o[6] = (bf16)b.z; o[7] = (bf16)b.w;
    *((bf16x8*)out + i) = o;
  }
}

// ------------- router: logits, top-2 weights; also X -> bf16 -------------
__global__ __launch_bounds__(256) void router_k(const float* __restrict__ X,
                                                const float* __restrict__ R,
                                                bf16* __restrict__ xbf,
                                                int* __restrict__ sel,
                                                float* __restrict__ wts) {
  int lane = threadIdx.x & 63;
  int t = blockIdx.x * 4 + (threadIdx.x >> 6);
  const float4* x4 = (const float4*)(X + (size_t)t * H_);
  bf16x4* xb4 = (bf16x4*)(xbf + (size_t)t * H_);
  float acc[E_];
#pragma unroll
  for (int e = 0; e < E_; ++e) acc[e] = 0.f;
#pragma unroll
  for (int i = 0; i < H_ / 256; ++i) {
    float4 x = x4[i * 64 + lane];
    bf16x4 xo; xo[0] = (bf16)x.x; xo[1] = (bf16)x.y; xo[2] = (bf16)x.z; xo[3] = (bf16)x.w;
    xb4[i * 64 + lane] = xo;
#pragma unroll
    for (int e = 0; e < E_; ++e) {
      float4 r = ((const float4*)(R + (size_t)e * H_))[i * 64 + lane];
      acc[e] += x.x * r.x + x.y * r.y + x.z * r.z + x.w * r.w;
    }
  }
#pragma unroll
  for (int e = 0; e < E_; ++e)
#pragma unroll
    for (int off = 32; off > 0; off >>= 1) acc[e] += __shfl_xor(acc[e], off);
  if (lane == 0) {
    int e1 = 0; float l1 = acc[0];
#pragma unroll
    for (int e = 1; e < E_; ++e) if (acc[e] > l1) { l1 = acc[e]; e1 = e; }
    int e2 = -1; float l2 = -3.4e38f;
#pragma unroll
    for (int e = 0; e < E_; ++e) if (e != e1 && acc[e] > l2) { l2 = acc[e]; e2 = e; }
    float d = expf(l2 - l1);
    float inv = 1.f / (1.f + d);
    sel[2 * t] = e1; sel[2 * t + 1] = e2;
    wts[2 * t] = inv; wts[2 * t + 1] = d * inv;
  }
}

// ---------------- routing bookkeeping ----------------
__global__ void count_k(const int* __restrict__ sel, int* __restrict__ ctl) {
  int i = blockIdx.x * blockDim.x + threadIdx.x;
  if (i < NSLOT) atomicAdd(&ctl[sel[i]], 1);
}
__global__ void prefix_k(int* __restrict__ ctl) {
  if (threadIdx.x == 0) {
    int off = 0;
    for (int e = 0; e < E_; ++e) { ctl[8 + e] = off; ctl[16 + e] = off; off += ctl[e]; }
  }
}
__global__ void scatter_k(const int* __restrict__ sel, const float* __restrict__ wts,
                          int* __restrict__ ctl, int* __restrict__ tok,
                          float* __restrict__ sw) {
  int i = blockIdx.x * blockDim.x + threadIdx.x;
  if (i < NSLOT) {
    int e = sel[i];
    int pos = atomicAdd(&ctl[16 + e], 1);
    tok[pos] = i >> 1;
    sw[pos] = wts[i];
  }
}

// quadrant fragment loads + MFMA (shared by both GEMMs)
#define QLOAD(cur, mh, nh)                                                   \
  _Pragma("unroll") for (int kk = 0; kk < 2; ++kk) {                         \
    _Pragma("unroll") for (int mm = 0; mm < 4; ++mm) {                       \
      int rowA = wr * 128 + (mh) * 64 + mm * 16 + lo;                        \
      af[mm][kk] = *(const bf16x8*)((const char*)lA[cur] + rowA * 128 +      \
                   (((kk * 4 + hi) ^ (rowA & 7)) * 16));                     \
    }                                                                        \
    _Pragma("unroll") for (int nn = 0; nn < 2; ++nn) {                       \
      int rowB = wc * 64 + (nh) * 32 + nn * 16 + lo;                         \
      bfr[nn][kk] = *(const bf16x8*)((const char*)lB[cur] + rowB * 128 +     \
                    (((kk * 4 + hi) ^ (rowB & 7)) * 16));                    \
    }                                                                        \
  }

#define QMFMA(mh, nh)                                                        \
  __builtin_amdgcn_s_setprio(1);                                             \
  _Pragma("unroll") for (int kk = 0; kk < 2; ++kk)                           \
    _Pragma("unroll") for (int mm = 0; mm < 4; ++mm)                         \
      _Pragma("unroll") for (int nn = 0; nn < 2; ++nn)                       \
        acc[(mh) * 4 + mm][(nh) * 2 + nn] =                                  \
            __builtin_amdgcn_mfma_f32_16x16x32_bf16(                         \
                af[mm][kk], bfr[nn][kk], acc[(mh) * 4 + mm][(nh) * 2 + nn],  \
                0, 0, 0);                                                    \
  __builtin_amdgcn_s_setprio(0);

// ---------------- GEMM1: act = silu(Xg @ Wg^T) * (Xg @ Wu^T) ----------------
// 256 token-rows x 256 B-rows (128 gate-j + 128 up-j interleaved per 16),
// BK=64, 8 waves, 4 quadrant phases per K-tile, dbuf LDS 128 KiB.
__global__ __launch_bounds__(512, 2) void gemm1_k(const bf16* __restrict__ Xb,
                                                  const bf16* __restrict__ Wgu,
                                                  const int* __restrict__ ctl,
                                                  const int* __restrict__ tok,
                                                  bf16* __restrict__ act) {
  constexpr int NMB = T_ / 256;        // 32
  constexpr int NJB = I_ / 128;        // 11
  constexpr int NB = NMB * NJB * E_;   // 2816
  constexpr int NT = H_ / 64;          // 32 K-tiles
  // XCD chunking over (j, e, m) order: m-inner => B-tile L2 reuse, experts
  // mixed within each XCD chunk => balanced.
  const int L0 = ((int)blockIdx.x & 7) * (NB >> 3) + ((int)blockIdx.x >> 3);
  const int m0 = (L0 % NMB) * 256;
  const int q = L0 / NMB;
  const int e = q % E_;
  const int j0 = (q / E_) * 128;
  const int cnt = ctl[e];
  if (m0 >= cnt) return;
  const int base = ctl[8 + e];

  __shared__ alignas(16) bf16 lA[2][256 * 64];
  __shared__ alignas(16) bf16 lB[2][256 * 64];

  const int t = threadIdx.x;
  const int lane = t & 63;
  const int wid = t >> 6;
  const int wr = wid >> 2;      // 0..1
  const int wc = wid & 3;       // 0..3
  const int lo = lane & 15, hi = lane >> 4;
  const bf16* wg = Wgu + (size_t)e * (2 * I_) * H_;

  // staging sources; XOR swizzle on the GLOBAL source chunk, LDS dest linear
  const bf16* asrc[4]; const bf16* bsrc[4]; int loff[4];
#pragma unroll
  for (int c = 0; c < 4; ++c) {
    int L = c * 512 + t;
    int row = L >> 3, cc = (L & 7) ^ (row & 7);
    loff[c] = L * 16;
    int r = m0 + row; if (r >= cnt) r = cnt - 1;
    asrc[c] = Xb + (size_t)tok[base + r] * H_ + cc * 8;
    // B rows interleave gate/up in 16-row groups: jsub pairs with epilogue
    int jsub = (row & 15) + ((row >> 5) << 4);
    const bf16* bb = (row & 16) ? wg + (size_t)(I_ + j0 + jsub) * H_
                                : wg + (size_t)(j0 + jsub) * H_;
    bsrc[c] = bb + cc * 8;
  }

#define STG1(b, kt)                                                   \
  {                                                                   \
    _Pragma("unroll") for (int c = 0; c < 4; ++c) {                   \
      gl2lds16(asrc[c] + (kt) * 64, (char*)lA[b] + loff[c]);          \
      gl2lds16(bsrc[c] + (kt) * 64, (char*)lB[b] + loff[c]);          \
    }                                                                 \
  }

  f32x4 zero = {0.f, 0.f, 0.f, 0.f};
  f32x4 acc[8][4];
#pragma unroll
  for (int m = 0; m < 8; ++m)
#pragma unroll
    for (int n = 0; n < 4; ++n) acc[m][n] = zero;

  STG1(0, 0);
  __syncthreads();

  for (int kt = 0; kt < NT; ++kt) {
    const int cur = kt & 1;
    bf16x8 af[4][2], bfr[2][2];
    // phase 1: quadrant (0,0) + stage next K-tile into the other buffer
    QLOAD(cur, 0, 0);
    if (kt + 1 < NT) STG1(cur ^ 1, kt + 1);
    bar_();
    QMFMA(0, 0);
    bar_();
    // phase 2
    QLOAD(cur, 1, 0);
    bar_();
    QMFMA(1, 0);
    bar_();
    // phase 3
    QLOAD(cur, 0, 1);
    bar_();
    QMFMA(0, 1);
    bar_();
    // phase 4: the only full drain (vmcnt+lgkm) -> next tile ready
    QLOAD(cur, 1, 1);
    __syncthreads();
    QMFMA(1, 1);
    bar_();
  }
#undef STG1

  // epilogue: acc[mi][ni]: ni even=gate, odd=up, same j per pair
#pragma unroll
  for (int mi = 0; mi < 8; ++mi) {
    int trl = wr * 128 + (mi >> 2) * 64 + (mi & 3) * 16 + hi * 4;
#pragma unroll
    for (int r = 0; r < 4; ++r) {
      int row = m0 + trl + r;
      if (row < cnt) {
        bf16* dst = act + (size_t)(base + row) * I_ + j0;
#pragma unroll
        for (int p = 0; p < 2; ++p) {
          float g = acc[mi][2 * p][r], u = acc[mi][2 * p + 1][r];
          dst[(wc * 2 + p) * 16 + lo] = (bf16)(g / (1.f + __expf(-g)) * u);
        }
      }
    }
  }
}

// ---------------- GEMM2: out[tok] += w * (act @ Wd^T) ----------------
// 256 slot-rows x 256 H-cols, BK=64, same phase structure, atomic adds.
__global__ __launch_bounds__(512, 2) void gemm2_k(const bf16* __restrict__ act,
                                                  const bf16* __restrict__ Wd,
                                                  const int* __restrict__ ctl,
                                                  const int* __restrict__ tok,
                                                  const float* __restrict__ sw,
                                                  float* __restrict__ out) {
  constexpr int NMB = T_ / 256;        // 32
  constexpr int NJB = H_ / 256;        // 8
  constexpr int NB = NMB * NJB * E_;   // 2048
  constexpr int NT = I_ / 64;          // 22 K-tiles
  const int L0 = ((int)blockIdx.x & 7) * (NB >> 3) + ((int)blockIdx.x >> 3);
  const int m0 = (L0 % NMB) * 256;
  const int q = L0 / NMB;
  const int e = q % E_;
  const int n0 = (q / E_) * 256;
  const int cnt = ctl[e];
  if (m0 >= cnt) return;
  const int base = ctl[8 + e];

  __shared__ alignas(16) bf16 lA[2][256 * 64];
  __shared__ alignas(16) bf16 lB[2][256 * 64];

  const int t = threadIdx.x;
  const int lane = t & 63;
  const int wid = t >> 6;
  const int wr = wid >> 2;
  const int wc = wid & 3;
  const int lo = lane & 15, hi = lane >> 4;
  const bf16* wd = Wd + (size_t)e * H_ * I_;

  const bf16* asrc[4]; const bf16* bsrc[4]; int loff[4];
#pragma unroll
  for (int c = 0; c < 4; ++c) {
    int L = c * 512 + t;
    int row = L >> 3, cc = (L & 7) ^ (row & 7);
    loff[c] = L * 16;
    int r = m0 + row; if (r >= cnt) r = cnt - 1;
    asrc[c] = act + (size_t)(base + r) * I_ + cc * 8;
    bsrc[c] = wd + (size_t)(n0 + row) * I_ + cc * 8;
  }

#define STG2(b, kt)                                                   \
  {                                                                   \
    _Pragma("unroll") for (int c = 0; c < 4; ++c) {                   \
      gl2lds16(asrc[c] + (kt) * 64, (char*)lA[b] + loff[c]);          \
      gl2lds16(bsrc[c] + (kt) * 64, (char*)lB[b] + loff[c]);          \
    }                                                                 \
  }

  f32x4 zero = {0.f, 0.f, 0.f, 0.f};
  f32x4 acc[8][4];
#pragma unroll
  for (int m = 0; m < 8; ++m)
#pragma unroll
    for (int n = 0; n < 4; ++n) acc[m][n] = zero;

  STG2(0, 0);
  __syncthreads();

  for (int kt = 0; kt < NT; ++kt) {
    const int cur = kt & 1;
    bf16x8 af[4][2], bfr[2][2];
    QLOAD(cur, 0, 0);
    if (kt + 1 < NT) STG2(cur ^ 1, kt + 1);
    bar_();
    QMFMA(0, 0);
    bar_();
    QLOAD(cur, 1, 0);
    bar_();
    QMFMA(1, 0);
    bar_();
    QLOAD(cur, 0, 1);
    bar_();
    QMFMA(0, 1);
    bar_();
    QLOAD(cur, 1, 1);
    __syncthreads();
    QMFMA(1, 1);
    bar_();
  }
#undef STG2

#pragma unroll
  for (int mi = 0; mi < 8; ++mi) {
    int trl = wr * 128 + (mi >> 2) * 64 + (mi & 3) * 16 + hi * 4;
#pragma unroll
    for (int r = 0; r < 4; ++r) {
      int row = m0 + trl + r;
      if (row < cnt) {
        int token = tok[base + row];
        float w = sw[base + row];
        float* dst = out + (size_t)token * H_ + n0;
#pragma unroll
        for (int ni = 0; ni < 4; ++ni) {
          int col = wc * 64 + (ni >> 1) * 32 + (ni & 1) * 16 + lo;
          atomicAdd(&dst[col], w * acc[mi][ni][r]);
        }
      }
    }
  }
}

// ---------------- host launch ----------------
extern "C" void kernel_launch(void* const* d_in, const int* in_sizes, int n_in,
                              void* d_out, int out_size, void* d_ws, size_t ws_size,
                              hipStream_t stream) {
  const float* X = (const float*)d_in[0];
  const float* R = (const float*)d_in[1];
  const float* Wgu = (const float*)d_in[2];
  const float* Wd = (const float*)d_in[3];
  float* out = (float*)d_out;

  char* ws = (char*)d_ws;
  size_t o = 0;
  auto alloc = [&](size_t sz) { void* p = ws + o; o += (sz + 255) & ~(size_t)255; return p; };
  bf16* wgu_bf = (bf16*)alloc(sizeof(bf16) * (size_t)E_ * 2 * I_ * H_);
  bf16* wd_bf  = (bf16*)alloc(sizeof(bf16) * (size_t)E_ * H_ * I_);
  bf16* xbf    = (bf16*)alloc(sizeof(bf16) * (size_t)T_ * H_);
  bf16* actb   = (bf16*)alloc(sizeof(bf16) * (size_t)NSLOT * I_);
  int* sel     = (int*)alloc(4 * NSLOT);
  float* wts   = (float*)alloc(4 * NSLOT);
  int* tokb    = (int*)alloc(4 * NSLOT);
  float* swb   = (float*)alloc(4 * NSLOT);
  int* ctl     = (int*)alloc(4 * 32);

  hipMemsetAsync(d_out, 0, sizeof(float) * (size_t)out_size, stream);
  hipMemsetAsync(ctl, 0, 4 * 32, stream);

  cvt_k<<<2048, 256, 0, stream>>>(Wgu, wgu_bf, (int)((size_t)E_ * 2 * I_ * H_ / 8));
  cvt_k<<<2048, 256, 0, stream>>>(Wd, wd_bf, (int)((size_t)E_ * H_ * I_ / 8));
  router_k<<<T_ / 4, 256, 0, stream>>>(X, R, xbf, sel, wts);
  count_k<<<NSLOT / 256, 256, 0, stream>>>(sel, ctl);
  prefix_k<<<1, 64, 0, stream>>>(ctl);
  scatter_k<<<NSLOT / 256, 256, 0, stream>>>(sel, wts, ctl, tokb, swb);
  gemm1_k<<<(T_ / 256) * (I_ / 128) * E_, 512, 0, stream>>>(xbf, wgu_bf, ctl, tokb, actb);
  gemm2_k<<<(T_ / 256) * (H_ / 256) * E_, 512, 0, stream>>>(actb, wd_bf, ctl, tokb, swb, out);
}